// Round 1
// baseline (177.982 us; speedup 1.0000x reference)
//
#include <hip/hip_runtime.h>

#define NPTS 2048
#define BW2 (0.05f * 0.05f)          // bandwidth^2, for labels / num_in
#define STOP2 (5e-5f * 5e-5f)        // (BANDWIDTH*0.001)^2 convergence threshold

// One mean-shift step: one wave per point, lanes split the j-loop.
// Convergence chain: reads dmax_prev (squared max step of previous iter);
// if < STOP2 the loop has terminated -> copy cur to nxt unchanged and do not
// write dmax_out (it stays 0, which keeps all later steps in copy mode too).
__global__ __launch_bounds__(256) void ms_step(
    const float* __restrict__ orig,
    const float* __restrict__ cur,
    float* __restrict__ nxt,
    unsigned* __restrict__ dmax_out,
    const unsigned* __restrict__ dmax_prev,
    int check_prev)
{
    __shared__ float lds[3 * NPTS];
    __shared__ unsigned sdmax;

    if (check_prev) {
        float prev = __uint_as_float(*dmax_prev);
        if (prev < STOP2) {
            // converged earlier: pass-through copy (uniform branch, no barriers)
            int g = blockIdx.x * 256 + threadIdx.x;
            if (g < 3 * NPTS) nxt[g] = cur[g];
            return;
        }
    }

    if (threadIdx.x == 0) sdmax = 0u;
    // stage original feats into LDS (AoS), float4 coalesced
    for (int t = threadIdx.x; t < 3 * NPTS / 4; t += 256)
        ((float4*)lds)[t] = ((const float4*)orig)[t];
    __syncthreads();

    int wid  = (blockIdx.x * 256 + threadIdx.x) >> 6;  // point index, 0..NPTS-1
    int lane = threadIdx.x & 63;

    // current position of this wave's point (uniform load, broadcast via cache)
    float xi = cur[3 * wid + 0];
    float yi = cur[3 * wid + 1];
    float zi = cur[3 * wid + 2];

    float ax = 0.f, ay = 0.f, az = 0.f, aw = 0.f;
    #pragma unroll 4
    for (int t = 0; t < NPTS / 64; ++t) {
        int j = t * 64 + lane;
        float px = lds[3 * j + 0];
        float py = lds[3 * j + 1];
        float pz = lds[3 * j + 2];
        float dx = xi - px, dy = yi - py, dz = zi - pz;
        float d2 = dx * dx + dy * dy + dz * dz;
        // KERN_SCALE cancels in shift = (w@feats)/sum(w); exp(-0.5*(d/0.05)^2)
        float w = __expf(-200.0f * d2);
        ax += w * px; ay += w * py; az += w * pz; aw += w;
    }
    #pragma unroll
    for (int off = 32; off > 0; off >>= 1) {
        ax += __shfl_down(ax, off);
        ay += __shfl_down(ay, off);
        az += __shfl_down(az, off);
        aw += __shfl_down(aw, off);
    }
    if (lane == 0) {
        float inv = 1.0f / aw;
        float nx = ax * inv, ny = ay * inv, nz = az * inv;
        nxt[3 * wid + 0] = nx;
        nxt[3 * wid + 1] = ny;
        nxt[3 * wid + 2] = nz;
        float ddx = nx - xi, ddy = ny - yi, ddz = nz - zi;
        float dd2 = ddx * ddx + ddy * ddy + ddz * ddz;
        atomicMax(&sdmax, __float_as_uint(dd2));   // non-negative: bit order == float order
    }
    __syncthreads();
    if (threadIdx.x == 0) atomicMax(dmax_out, sdmax);
}

// num_in[i] = #{ j : dist(orig_i, orig_j) < bandwidth }  (self included)
__global__ __launch_bounds__(256) void ms_numin(
    const float* __restrict__ orig, int* __restrict__ num_in)
{
    __shared__ float lds[3 * NPTS];
    for (int t = threadIdx.x; t < 3 * NPTS / 4; t += 256)
        ((float4*)lds)[t] = ((const float4*)orig)[t];
    __syncthreads();

    int wid  = (blockIdx.x * 256 + threadIdx.x) >> 6;
    int lane = threadIdx.x & 63;
    float xi = lds[3 * wid + 0];
    float yi = lds[3 * wid + 1];
    float zi = lds[3 * wid + 2];

    int cnt = 0;
    #pragma unroll 4
    for (int t = 0; t < NPTS / 64; ++t) {
        int j = t * 64 + lane;
        float dx = xi - lds[3 * j + 0];
        float dy = yi - lds[3 * j + 1];
        float dz = zi - lds[3 * j + 2];
        float d2 = dx * dx + dy * dy + dz * dz;
        cnt += (d2 < BW2) ? 1 : 0;
    }
    #pragma unroll
    for (int off = 32; off > 0; off >>= 1) cnt += __shfl_down(cnt, off);
    if (lane == 0) num_in[wid] = cnt;
}

// argmax(num_in) with FIRST-max tie-break (jnp.argmax semantics), then
// center = converged feats[max_idx], labels = dist(orig[max_idx], orig) < bw
__global__ __launch_bounds__(256) void ms_finalize(
    const float* __restrict__ orig,
    const float* __restrict__ fin,
    const int* __restrict__ num_in,
    float* __restrict__ out)
{
    __shared__ int swk[4];
    int t = threadIdx.x;
    int best = -1;
    for (int i = t; i < NPTS; i += 256) {
        // key: higher count wins; tie -> smaller index wins (first max)
        int key = (num_in[i] << 12) | (4095 - i);
        best = best > key ? best : key;
    }
    #pragma unroll
    for (int off = 32; off > 0; off >>= 1) {
        int o = __shfl_down(best, off);
        best = best > o ? best : o;
    }
    if ((t & 63) == 0) swk[t >> 6] = best;
    __syncthreads();
    int b0 = swk[0] > swk[1] ? swk[0] : swk[1];
    int b1 = swk[2] > swk[3] ? swk[2] : swk[3];
    int gbest = b0 > b1 ? b0 : b1;
    int max_idx = 4095 - (gbest & 4095);

    float cx = orig[3 * max_idx + 0];
    float cy = orig[3 * max_idx + 1];
    float cz = orig[3 * max_idx + 2];

    if (t < 3) out[t] = fin[3 * max_idx + t];

    for (int i = t; i < NPTS; i += 256) {
        float dx = orig[3 * i + 0] - cx;
        float dy = orig[3 * i + 1] - cy;
        float dz = orig[3 * i + 2] - cz;
        float d2 = dx * dx + dy * dy + dz * dz;
        out[3 + i] = (d2 < BW2) ? 1.0f : 0.0f;
    }
}

extern "C" void kernel_launch(void* const* d_in, const int* in_sizes, int n_in,
                              void* d_out, int out_size, void* d_ws, size_t ws_size,
                              hipStream_t stream)
{
    const float* feats = (const float*)d_in[0];
    float* out = (float*)d_out;

    // workspace layout
    float* bufA = (float*)d_ws;                       // [NPTS*3]
    float* bufB = bufA + 3 * NPTS;                    // [NPTS*3]
    unsigned* dmax = (unsigned*)(bufB + 3 * NPTS);    // [16] squared max-step per iter
    int* num_in = (int*)(dmax + 16);                  // [NPTS]

    hipMemsetAsync(dmax, 0, 16 * sizeof(unsigned), stream);

    dim3 grid(NPTS / 4);   // 512 blocks x 4 waves = one wave per point
    dim3 block(256);

    // do-while: at most 11 update steps (it = 0..10 enter body)
    for (int k = 0; k <= 10; ++k) {
        const float* src = (k == 0) ? feats : ((k & 1) ? bufA : bufB);
        float* dst = (k & 1) ? bufB : bufA;
        ms_step<<<grid, block, 0, stream>>>(feats, src, dst, dmax + k,
                                            (k > 0) ? (dmax + k - 1) : dmax,
                                            k > 0 ? 1 : 0);
    }
    // 11 steps: k=10 (even) wrote bufA -> final positions live in bufA
    ms_numin<<<grid, block, 0, stream>>>(feats, num_in);
    ms_finalize<<<1, block, 0, stream>>>(feats, bufA, num_in, out);
}

// Round 2
// 112.480 us; speedup vs baseline: 1.5823x; 1.5823x over previous
//
#include <hip/hip_runtime.h>

#define NPTS 2048
#define ITERS 11                      // do-while runs at most 11 update steps
#define BW2 (0.05f * 0.05f)           // bandwidth^2 (labels / num_in)
#define STOP2 (5e-5f * 5e-5f)         // (BANDWIDTH*0.001)^2 convergence threshold

// One wave per point; lanes split the j-loop over the 2048 ORIGINAL points
// (which stay fixed in LDS). Each wave iterates its point 11 times entirely in
// registers -- trajectories are independent, so no cross-wave sync is needed.
// Per iteration we record the point's new position and its squared step size;
// the tiny finalize kernel decides which iteration the do-while would have
// stopped at. Everything kernel B reads is unconditionally written here, so
// no workspace init / atomics / memsets are required.
__global__ __launch_bounds__(256) void ms_iter(
    const float* __restrict__ orig,
    float* __restrict__ traj,        // [ITERS][NPTS][3]
    unsigned* __restrict__ wdelta,   // [ITERS][NPTS]  (dd2 as float bits)
    int* __restrict__ wkey)          // [NPTS] selection keys (cnt<<12 | 4095-i)
{
    __shared__ float lds[3 * NPTS];  // 24 KB: original feats, AoS
    for (int t = threadIdx.x; t < 3 * NPTS / 4; t += 256)
        ((float4*)lds)[t] = ((const float4*)orig)[t];
    __syncthreads();

    int wid  = (blockIdx.x * 256 + threadIdx.x) >> 6;  // this wave's point
    int lane = threadIdx.x & 63;

    float xi = lds[3 * wid + 0];
    float yi = lds[3 * wid + 1];
    float zi = lds[3 * wid + 2];

    for (int k = 0; k < ITERS; ++k) {
        float ax = 0.f, ay = 0.f, az = 0.f, aw = 0.f;
        // bank note: addr stride 3 floats/lane, 3 coprime 32 -> 2 lanes/bank
        // (wave64 minimum, free per m136)
        #pragma unroll 4
        for (int t = 0; t < NPTS / 64; ++t) {
            int j = t * 64 + lane;
            float px = lds[3 * j + 0];
            float py = lds[3 * j + 1];
            float pz = lds[3 * j + 2];
            float dx = xi - px, dy = yi - py, dz = zi - pz;
            // KERN_SCALE cancels between numerator and denominator
            float w = __expf(-200.0f * (dx * dx + dy * dy + dz * dz));
            ax += w * px; ay += w * py; az += w * pz; aw += w;
        }
        // butterfly: ALL lanes end with the full sums -> no broadcast needed
        #pragma unroll
        for (int off = 32; off; off >>= 1) {
            ax += __shfl_xor(ax, off);
            ay += __shfl_xor(ay, off);
            az += __shfl_xor(az, off);
            aw += __shfl_xor(aw, off);
        }
        float inv = 1.0f / aw;
        float nx = ax * inv, ny = ay * inv, nz = az * inv;
        float ddx = nx - xi, ddy = ny - yi, ddz = nz - zi;
        float dd2 = ddx * ddx + ddy * ddy + ddz * ddz;
        if (lane == 0) {
            traj[(k * NPTS + wid) * 3 + 0] = nx;
            traj[(k * NPTS + wid) * 3 + 1] = ny;
            traj[(k * NPTS + wid) * 3 + 2] = nz;
            // dd2 >= 0 -> float order == unsigned bit order
            wdelta[k * NPTS + wid] = __float_as_uint(dd2);
        }
        xi = nx; yi = ny; zi = nz;
    }

    // selection pass on ORIGINAL feats (independent of the iteration)
    float ox = lds[3 * wid + 0];
    float oy = lds[3 * wid + 1];
    float oz = lds[3 * wid + 2];
    int cnt = 0;
    #pragma unroll 4
    for (int t = 0; t < NPTS / 64; ++t) {
        int j = t * 64 + lane;
        float dx = ox - lds[3 * j + 0];
        float dy = oy - lds[3 * j + 1];
        float dz = oz - lds[3 * j + 2];
        cnt += (dx * dx + dy * dy + dz * dz < BW2) ? 1 : 0;
    }
    #pragma unroll
    for (int off = 32; off; off >>= 1) cnt += __shfl_xor(cnt, off);
    if (lane == 0)
        wkey[wid] = (cnt << 12) | (4095 - wid);  // higher cnt, then lower idx
}

// Single block: reduce per-iteration deltas -> k*, reduce keys -> max_idx,
// emit center = traj[k*][max_idx] and labels vs orig[max_idx].
__global__ __launch_bounds__(256) void ms_final(
    const float* __restrict__ orig,
    const float* __restrict__ traj,
    const unsigned* __restrict__ wdelta,
    const int* __restrict__ wkey,
    float* __restrict__ out)
{
    __shared__ unsigned redu[4];
    __shared__ int redi[4];
    __shared__ float dmaxs[ITERS];
    __shared__ int skstar, smaxidx;

    int t = threadIdx.x, lane = t & 63, w = t >> 6;

    // global max step^2 per iteration
    for (int k = 0; k < ITERS; ++k) {
        unsigned m = 0;
        for (int i = t; i < NPTS; i += 256) {
            unsigned v = wdelta[k * NPTS + i];
            m = v > m ? v : m;
        }
        #pragma unroll
        for (int off = 32; off; off >>= 1) {
            unsigned o = __shfl_xor(m, off);
            m = o > m ? o : m;
        }
        if (lane == 0) redu[w] = m;
        __syncthreads();
        if (t == 0) {
            unsigned a = redu[0] > redu[1] ? redu[0] : redu[1];
            unsigned b = redu[2] > redu[3] ? redu[2] : redu[3];
            dmaxs[k] = __uint_as_float(a > b ? a : b);
        }
        __syncthreads();
    }

    // argmax(num_in) with first-max tie-break
    int best = -1;
    for (int i = t; i < NPTS; i += 256) {
        int v = wkey[i];
        best = v > best ? v : best;
    }
    #pragma unroll
    for (int off = 32; off; off >>= 1) {
        int o = __shfl_xor(best, off);
        best = o > best ? o : best;
    }
    if (lane == 0) redi[w] = best;
    __syncthreads();
    if (t == 0) {
        int a = redi[0] > redi[1] ? redi[0] : redi[1];
        int b = redi[2] > redi[3] ? redi[2] : redi[3];
        int g = a > b ? a : b;
        smaxidx = 4095 - (g & 4095);
        // do-while stops after first step whose global max delta < thresh
        int ks = ITERS - 1;
        for (int k = 0; k < ITERS; ++k)
            if (dmaxs[k] < STOP2) { ks = k; break; }
        skstar = ks;
    }
    __syncthreads();

    int max_idx = smaxidx, kstar = skstar;
    if (t < 3) out[t] = traj[(kstar * NPTS + max_idx) * 3 + t];

    float cx = orig[3 * max_idx + 0];
    float cy = orig[3 * max_idx + 1];
    float cz = orig[3 * max_idx + 2];
    for (int i = t; i < NPTS; i += 256) {
        float dx = orig[3 * i + 0] - cx;
        float dy = orig[3 * i + 1] - cy;
        float dz = orig[3 * i + 2] - cz;
        out[3 + i] = (dx * dx + dy * dy + dz * dz < BW2) ? 1.0f : 0.0f;
    }
}

extern "C" void kernel_launch(void* const* d_in, const int* in_sizes, int n_in,
                              void* d_out, int out_size, void* d_ws, size_t ws_size,
                              hipStream_t stream)
{
    const float* feats = (const float*)d_in[0];
    float* out = (float*)d_out;

    // workspace layout (everything written before read -> no init needed)
    float* traj = (float*)d_ws;                          // ITERS*NPTS*3 floats
    unsigned* wdelta = (unsigned*)(traj + ITERS * NPTS * 3); // ITERS*NPTS
    int* wkey = (int*)(wdelta + ITERS * NPTS);           // NPTS

    ms_iter<<<dim3(NPTS / 4), dim3(256), 0, stream>>>(feats, traj, wdelta, wkey);
    ms_final<<<dim3(1), dim3(256), 0, stream>>>(feats, traj, wdelta, wkey, out);
}

// Round 3
// 83.324 us; speedup vs baseline: 2.1360x; 1.3499x over previous
//
#include <hip/hip_runtime.h>

#define NPTS 2048
#define ITERS 11                      // do-while runs at most 11 update steps
#define BW2 (0.05f * 0.05f)           // bandwidth^2 (labels / num_in)
#define STOP2 (5e-5f * 5e-5f)         // (BANDWIDTH*0.001)^2 convergence threshold
#define NEG_K 288.539008f             // 200 / ln(2)
#define POS_2K 577.078016f            // 400 / ln(2)

// One wave per point. Each lane caches its 32 fixed j-points (x,y,z,q) in
// REGISTERS once, then all 11 iterations run entirely out of VGPRs -- no LDS
// traffic in the main loop (R2 version was LDS-BW bound re-reading 24KB/iter).
// w = exp(-200*d^2) refactored as exp2(q_j + qx + 577.078*(x.p)) with
// q_j = -288.539*|p_j|^2 (per-lane constant), qx = -288.539*|x|^2 (uniform
// per iteration). Argument stays in [-866, 0] -> no overflow; KERN_SCALE and
// the common factor cancel in the weighted-mean ratio.
// Reductions (global max step^2 per iter, argmax key) are pre-reduced per
// block in LDS and pushed with signed-int atomicMax: all values are >= 0 and
// both possible initial ws states (0xAAAAAAAA = negative, or 0) are absorbed
// by max -- no init dispatch needed.
__global__ __launch_bounds__(256) void ms_iter(
    const float* __restrict__ orig,
    float* __restrict__ traj,        // [ITERS][NPTS][3]
    int* __restrict__ gdmax,         // [ITERS]  max dd2 bits (float>=0 -> int order ok)
    int* __restrict__ gkey)          // [1]      max selection key
{
    __shared__ int sdd[ITERS];
    __shared__ int skey;
    int t = threadIdx.x;
    if (t < ITERS) sdd[t] = 0;
    if (t == ITERS) skey = 0;
    __syncthreads();

    int wid  = (blockIdx.x * 256 + t) >> 6;   // this wave's point
    int lane = t & 63;

    // register-cached j-data: lane L owns j = L, L+64, ..., L+31*64
    float px[32], py[32], pz[32], qj[32];
    #pragma unroll
    for (int u = 0; u < 32; ++u) {
        int j = u * 64 + lane;
        float a = orig[3 * j + 0];
        float b = orig[3 * j + 1];
        float c = orig[3 * j + 2];
        px[u] = a; py[u] = b; pz[u] = c;
        qj[u] = -NEG_K * (a * a + b * b + c * c);
    }

    float ox = orig[3 * wid + 0];   // wave-uniform -> scalar loads
    float oy = orig[3 * wid + 1];
    float oz = orig[3 * wid + 2];
    float xi = ox, yi = oy, zi = oz;

    for (int k = 0; k < ITERS; ++k) {
        float xs = POS_2K * xi, ys = POS_2K * yi, zs = POS_2K * zi;
        float qx = -NEG_K * (xi * xi + yi * yi + zi * zi);
        float ax = 0.f, ay = 0.f, az = 0.f, aw = 0.f;
        #pragma unroll
        for (int u = 0; u < 32; ++u) {
            float s = qj[u] + qx;
            s = fmaf(px[u], xs, s);
            s = fmaf(py[u], ys, s);
            s = fmaf(pz[u], zs, s);
            float w = __builtin_amdgcn_exp2f(s);   // v_exp_f32
            ax = fmaf(w, px[u], ax);
            ay = fmaf(w, py[u], ay);
            az = fmaf(w, pz[u], az);
            aw += w;
        }
        #pragma unroll
        for (int off = 32; off; off >>= 1) {
            ax += __shfl_xor(ax, off);
            ay += __shfl_xor(ay, off);
            az += __shfl_xor(az, off);
            aw += __shfl_xor(aw, off);
        }
        float inv = 1.0f / aw;
        float nx = ax * inv, ny = ay * inv, nz = az * inv;
        float ddx = nx - xi, ddy = ny - yi, ddz = nz - zi;
        float dd2 = ddx * ddx + ddy * ddy + ddz * ddz;
        if (lane == 0) {
            traj[(k * NPTS + wid) * 3 + 0] = nx;
            traj[(k * NPTS + wid) * 3 + 1] = ny;
            traj[(k * NPTS + wid) * 3 + 2] = nz;
            atomicMax(&sdd[k], __float_as_int(dd2));   // dd2>=0 -> bit order ok
        }
        xi = nx; yi = ny; zi = nz;
    }

    // selection pass on ORIGINAL feats -- data already in registers
    int cnt = 0;
    #pragma unroll
    for (int u = 0; u < 32; ++u) {
        float dx = ox - px[u], dy = oy - py[u], dz = oz - pz[u];
        cnt += (dx * dx + dy * dy + dz * dz < BW2) ? 1 : 0;
    }
    #pragma unroll
    for (int off = 32; off; off >>= 1) cnt += __shfl_xor(cnt, off);
    if (lane == 0)
        atomicMax(&skey, (cnt << 12) | (4095 - wid));  // higher cnt, then lower idx

    __syncthreads();
    if (t < ITERS) atomicMax(&gdmax[t], sdd[t]);
    if (t == ITERS) atomicMax(gkey, skey);
}

// Tiny: pick k* (first iteration with global max step^2 < STOP2, else last),
// pick max_idx from the key, emit center + labels.
__global__ __launch_bounds__(256) void ms_final(
    const float* __restrict__ orig,
    const float* __restrict__ traj,
    const int* __restrict__ gdmax,
    const int* __restrict__ gkey,
    float* __restrict__ out)
{
    __shared__ int sk, sm;
    int t = threadIdx.x;
    if (t == 0) {
        int ks = ITERS - 1;
        for (int k = 0; k < ITERS; ++k)
            if (__int_as_float(gdmax[k]) < STOP2) { ks = k; break; }
        sk = ks;
        sm = 4095 - (*gkey & 4095);
    }
    __syncthreads();
    int kstar = sk, mi = sm;

    if (t < 3) out[t] = traj[(kstar * NPTS + mi) * 3 + t];

    float cx = orig[3 * mi + 0];
    float cy = orig[3 * mi + 1];
    float cz = orig[3 * mi + 2];
    for (int i = t; i < NPTS; i += 256) {
        float dx = orig[3 * i + 0] - cx;
        float dy = orig[3 * i + 1] - cy;
        float dz = orig[3 * i + 2] - cz;
        out[3 + i] = (dx * dx + dy * dy + dz * dz < BW2) ? 1.0f : 0.0f;
    }
}

extern "C" void kernel_launch(void* const* d_in, const int* in_sizes, int n_in,
                              void* d_out, int out_size, void* d_ws, size_t ws_size,
                              hipStream_t stream)
{
    const float* feats = (const float*)d_in[0];
    float* out = (float*)d_out;

    float* traj = (float*)d_ws;                       // ITERS*NPTS*3 floats
    int* gdmax = (int*)(traj + ITERS * NPTS * 3);     // ITERS
    int* gkey = gdmax + ITERS;                        // 1

    ms_iter<<<dim3(NPTS / 4), dim3(256), 0, stream>>>(feats, traj, gdmax, gkey);
    ms_final<<<dim3(1), dim3(256), 0, stream>>>(feats, traj, gdmax, gkey, out);
}

// Round 4
// 82.785 us; speedup vs baseline: 2.1499x; 1.0065x over previous
//
#include <hip/hip_runtime.h>

#define NPTS 2048
#define NBLK 512                      // NPTS/4 blocks, one wave per point
#define ITERS 11                      // do-while runs at most 11 update steps
#define NSLOT 12                      // 11 dmax slots + 1 key slot
#define BW2 (0.05f * 0.05f)           // bandwidth^2 (labels / num_in)
#define STOP2 (5e-5f * 5e-5f)         // (BANDWIDTH*0.001)^2 convergence threshold
#define NEG_K 288.539008f             // 200 / ln(2)
#define POS_2K 577.078016f            // 400 / ln(2)

// One wave per point; each lane register-caches its 32 fixed j-points as
// float2 PAIRS so the compiler can form double-rate v_pk_fma_f32 (gfx950
// packed fp32). All 11 iterations run out of VGPRs; no LDS in the main loop.
// w = exp(-200 d^2) = exp2(qj + qx + 577.078*(x.p)), qj/qx precomputed.
// Per-block reductions (max step^2 per iter, selection key) are pre-reduced
// in LDS and PLAIN-STORED transposed into gblk[slot][block] -- every entry is
// unconditionally written, so no init dispatch and no global atomics (the R3
// version funneled 512 blocks x 12 atomicMax onto 12 dwords -> serialized
// L2 tail gating ms_final).
__global__ __launch_bounds__(256) void ms_iter(
    const float* __restrict__ orig,
    float* __restrict__ traj,        // [ITERS][NPTS][3]
    int* __restrict__ gblk)          // [NSLOT][NBLK]
{
    __shared__ int sred[NSLOT];
    int t = threadIdx.x;
    if (t < NSLOT) sred[t] = 0;      // all reduced values are >= 0
    __syncthreads();

    int wid  = (blockIdx.x * 256 + t) >> 6;   // this wave's point
    int lane = t & 63;

    // register j-cache: lane L owns pairs (128u+L, 128u+64+L), u = 0..15
    float2 px[16], py[16], pz[16], qj[16];
    #pragma unroll
    for (int u = 0; u < 16; ++u) {
        int j0 = u * 128 + lane;
        int j1 = j0 + 64;
        float a0 = orig[3 * j0 + 0], b0 = orig[3 * j0 + 1], c0 = orig[3 * j0 + 2];
        float a1 = orig[3 * j1 + 0], b1 = orig[3 * j1 + 1], c1 = orig[3 * j1 + 2];
        px[u] = make_float2(a0, a1);
        py[u] = make_float2(b0, b1);
        pz[u] = make_float2(c0, c1);
        qj[u] = make_float2(-NEG_K * (a0 * a0 + b0 * b0 + c0 * c0),
                            -NEG_K * (a1 * a1 + b1 * b1 + c1 * c1));
    }

    float ox = orig[3 * wid + 0];
    float oy = orig[3 * wid + 1];
    float oz = orig[3 * wid + 2];
    float xi = ox, yi = oy, zi = oz;

    for (int k = 0; k < ITERS; ++k) {
        float xs = POS_2K * xi, ys = POS_2K * yi, zs = POS_2K * zi;
        float qx = -NEG_K * (xi * xi + yi * yi + zi * zi);
        float axx = 0.f, axy = 0.f, ayx = 0.f, ayy = 0.f;
        float azx = 0.f, azy = 0.f, awx = 0.f, awy = 0.f;
        #pragma unroll
        for (int u = 0; u < 16; ++u) {
            float sx = qj[u].x + qx;
            float sy = qj[u].y + qx;
            sx = fmaf(px[u].x, xs, sx);  sy = fmaf(px[u].y, xs, sy);
            sx = fmaf(py[u].x, ys, sx);  sy = fmaf(py[u].y, ys, sy);
            sx = fmaf(pz[u].x, zs, sx);  sy = fmaf(pz[u].y, zs, sy);
            float wx = __builtin_amdgcn_exp2f(sx);
            float wy = __builtin_amdgcn_exp2f(sy);
            axx = fmaf(wx, px[u].x, axx);  axy = fmaf(wy, px[u].y, axy);
            ayx = fmaf(wx, py[u].x, ayx);  ayy = fmaf(wy, py[u].y, ayy);
            azx = fmaf(wx, pz[u].x, azx);  azy = fmaf(wy, pz[u].y, azy);
            awx += wx;                     awy += wy;
        }
        float ax = axx + axy, ay = ayx + ayy, az = azx + azy, aw = awx + awy;
        #pragma unroll
        for (int off = 32; off; off >>= 1) {
            ax += __shfl_xor(ax, off);
            ay += __shfl_xor(ay, off);
            az += __shfl_xor(az, off);
            aw += __shfl_xor(aw, off);
        }
        float inv = 1.0f / aw;
        float nx = ax * inv, ny = ay * inv, nz = az * inv;
        float ddx = nx - xi, ddy = ny - yi, ddz = nz - zi;
        float dd2 = ddx * ddx + ddy * ddy + ddz * ddz;
        if (lane == 0) {
            traj[(k * NPTS + wid) * 3 + 0] = nx;
            traj[(k * NPTS + wid) * 3 + 1] = ny;
            traj[(k * NPTS + wid) * 3 + 2] = nz;
            atomicMax(&sred[k], __float_as_int(dd2));  // LDS atomic, 4 waves only
        }
        xi = nx; yi = ny; zi = nz;
    }

    // selection pass on ORIGINAL feats -- data already in registers
    int cnt = 0;
    #pragma unroll
    for (int u = 0; u < 16; ++u) {
        float dx0 = ox - px[u].x, dy0 = oy - py[u].x, dz0 = oz - pz[u].x;
        float dx1 = ox - px[u].y, dy1 = oy - py[u].y, dz1 = oz - pz[u].y;
        cnt += (dx0 * dx0 + dy0 * dy0 + dz0 * dz0 < BW2) ? 1 : 0;
        cnt += (dx1 * dx1 + dy1 * dy1 + dz1 * dz1 < BW2) ? 1 : 0;
    }
    #pragma unroll
    for (int off = 32; off; off >>= 1) cnt += __shfl_xor(cnt, off);
    if (lane == 0)
        atomicMax(&sred[11], (cnt << 12) | (4095 - wid));  // higher cnt, then lower idx

    __syncthreads();
    // transposed plain store: slot-major so ms_final reads coalesced
    if (t < NSLOT) gblk[t * NBLK + blockIdx.x] = sred[t];
}

// Parallel 512-way max per slot, then emit center + labels.
__global__ __launch_bounds__(256) void ms_final(
    const float* __restrict__ orig,
    const float* __restrict__ traj,
    const int* __restrict__ gblk,
    float* __restrict__ out)
{
    __shared__ int red[NSLOT];
    __shared__ int sk, sm;
    int t = threadIdx.x, lane = t & 63;
    if (t < NSLOT) red[t] = 0;
    __syncthreads();

    // slots 0..11: 512 values each; 2 coalesced loads + shuffle tree
    #pragma unroll
    for (int s = 0; s < NSLOT; ++s) {
        int a = gblk[s * NBLK + t];
        int b = gblk[s * NBLK + t + 256];
        int m = a > b ? a : b;
        #pragma unroll
        for (int off = 32; off; off >>= 1) {
            int o = __shfl_xor(m, off);
            m = o > m ? o : m;
        }
        if (lane == 0) atomicMax(&red[s], m);   // 4 waves, LDS atomic
    }
    __syncthreads();

    if (t == 0) {
        int ks = ITERS - 1;
        for (int k = 0; k < ITERS; ++k)
            if (__int_as_float(red[k]) < STOP2) { ks = k; break; }
        sk = ks;
        sm = 4095 - (red[11] & 4095);
    }
    __syncthreads();
    int kstar = sk, mi = sm;

    if (t < 3) out[t] = traj[(kstar * NPTS + mi) * 3 + t];

    float cx = orig[3 * mi + 0];
    float cy = orig[3 * mi + 1];
    float cz = orig[3 * mi + 2];
    for (int i = t; i < NPTS; i += 256) {
        float dx = orig[3 * i + 0] - cx;
        float dy = orig[3 * i + 1] - cy;
        float dz = orig[3 * i + 2] - cz;
        out[3 + i] = (dx * dx + dy * dy + dz * dz < BW2) ? 1.0f : 0.0f;
    }
}

extern "C" void kernel_launch(void* const* d_in, const int* in_sizes, int n_in,
                              void* d_out, int out_size, void* d_ws, size_t ws_size,
                              hipStream_t stream)
{
    const float* feats = (const float*)d_in[0];
    float* out = (float*)d_out;

    float* traj = (float*)d_ws;                       // ITERS*NPTS*3 floats
    int* gblk = (int*)(traj + ITERS * NPTS * 3);      // NSLOT*NBLK ints

    ms_iter<<<dim3(NBLK), dim3(256), 0, stream>>>(feats, traj, gblk);
    ms_final<<<dim3(1), dim3(256), 0, stream>>>(feats, traj, gblk, out);
}